// Round 5
// baseline (186.333 us; speedup 1.0000x reference)
//
#include <hip/hip_runtime.h>
#include <hip/hip_bf16.h>

// B=32, CQ=256, CC=3, COUT=256, H=W=32, HW=1024, INTER=128
//
// Math (verified rounds 0-5, absmax 0.031):
//   scores[i,j] = a[:,i]·ctx[:,j] + c_i (softmax-invariant const dropped)
//     a = M·Q + m0, M = Wk^T Wq (3x256)
//   fused = Wp·Q + G·cp + g0;  G = Wp·Wv (256x3), cp[t,i] = sum_j ctx[t,j]P[i,j]
//   resize 224->32 half-pixel = exact gather at (7y+3, 7x+3).
//
// R10: R9 post-mortem -- grid=512 on 256 CUs means 2 blocks/CU is ALL the
// grid provides; LDS diet to 3/CU was a no-op (occupancy 15.2% unchanged).
// Fused wall time = one block's serial 7-phase latency (58us, 77% no-issue).
// Fix: split the two independent dataflows into two 1024-block kernels:
//   sca_attn: a=M.Q -> softmax vs LDS ctx -> cp to ws   (no MFMA/pack)
//   sca_gemm: Q -> bf16 QL -> MFMA Wp.Q -> +G.cp + stats (ONE barrier)
// Each: i-tile 32, 4 blocks/CU, short chains. Q read 2x but L3-resident.
//
// Workspace (float offsets):
#define WS_M4    0        // M4[c] = {m0,m1,m2,0}  c<256  (float4)
#define WS_M0    1024     // m0[3]
#define WS_G4    1056     // G4[o] = {G0,G1,G2,g0} (float4)
#define WS_BSUM  2080     // [32]
#define WS_BSSQ  2112     // [32]
#define WS_WPB   2144     // Wp bf16 fragment-packed [o_tile16][kt8][lane64][8]
#define WS_CP    34912    // cp float4 {p0,p1,p2,0} [b32][i1024]  (512 KB)
#define WS_CTX   165984   // ctx float4 {c0,c1,c2,0} [b32][j1024] (512 KB)

typedef __attribute__((ext_vector_type(8))) short short8;
typedef __attribute__((ext_vector_type(4))) float floatx4;

__device__ inline unsigned short f2bf(float x) {
    unsigned u = __float_as_uint(x);
    return (unsigned short)((u + 0x7FFFu + ((u >> 16) & 1u)) >> 16);
}

// ---------- K0: weight precompute + Wp fragment-pack + ctx pre-gather ----------
// blocks 0..3: M quarters (float4 layout); block 0 also m0 + stats zero
// blocks 4..35: Wp bf16 pack + G = Wp*Wv via lane reduction
// blocks 36..163: ctx bilinear-gather -> ws
__global__ __launch_bounds__(256) void sca_pre(
    const float* __restrict__ Wq, const float* __restrict__ bq,
    const float* __restrict__ Wk, const float* __restrict__ bk,
    const float* __restrict__ Wv, const float* __restrict__ bv,
    const float* __restrict__ Wp, const float* __restrict__ bp,
    const float* __restrict__ ctxin, float* __restrict__ ws)
{
    int tid = threadIdx.x;
    int blk = blockIdx.x;
    if (blk < 4) {
        __shared__ float WkL[384];
        __shared__ float bqL[128];
        __shared__ float redM[4][64][3];
        int o0 = blk << 6;
        if (tid < 128) bqL[tid] = bq[tid];
        for (int idx = tid; idx < 384; idx += 256) WkL[idx] = Wk[idx];
        __syncthreads();
        int o64 = tid & 63, cg = tid >> 6;
        float m0v = 0.f, m1v = 0.f, m2v = 0.f;
        for (int c0 = cg * 32; c0 < cg * 32 + 32; c0 += 16) {
            float q[16];
#pragma unroll
            for (int j = 0; j < 16; ++j) q[j] = Wq[(c0 + j) * 256 + o0 + o64];
#pragma unroll
            for (int j = 0; j < 16; ++j) {
                int c = c0 + j;
                m0v = fmaf(WkL[c * 3 + 0], q[j], m0v);
                m1v = fmaf(WkL[c * 3 + 1], q[j], m1v);
                m2v = fmaf(WkL[c * 3 + 2], q[j], m2v);
            }
        }
        redM[cg][o64][0] = m0v; redM[cg][o64][1] = m1v; redM[cg][o64][2] = m2v;
        __syncthreads();
        if (tid < 64) {
            float r0 = redM[0][tid][0] + redM[1][tid][0] + redM[2][tid][0] + redM[3][tid][0];
            float r1 = redM[0][tid][1] + redM[1][tid][1] + redM[2][tid][1] + redM[3][tid][1];
            float r2 = redM[0][tid][2] + redM[1][tid][2] + redM[2][tid][2] + redM[3][tid][2];
            ((float4*)(ws + WS_M4))[o0 + tid] = make_float4(r0, r1, r2, 0.f);
        }
        if (blk == 0) {
            if (tid < 3) {
                float s = 0.f;
                for (int c = 0; c < 128; ++c) s = fmaf(WkL[c * 3 + tid], bqL[c], s);
                ws[WS_M0 + tid] = s;
            }
            if (tid < 64) ws[WS_BSUM + tid] = 0.f;   // bsum[32]+bssq[32]
        }
    } else if (blk < 36) {
        __shared__ float WvL[768];
        __shared__ float bvL[256];
        for (int idx = tid; idx < 768; idx += 256) WvL[idx] = Wv[idx];
        bvL[tid] = bv[tid];
        __syncthreads();
        int idx = (blk - 4) * 2048 + tid * 8;       // flat [o][k] element index
        int o = idx >> 8;
        int kt = (tid & 31) >> 2, quad = tid & 3;
        const float4* s = (const float4*)(Wp + idx);
        float4 x0 = s[0], x1 = s[1];
        uint4 v;
        v.x = (unsigned)f2bf(x0.x) | ((unsigned)f2bf(x0.y) << 16);
        v.y = (unsigned)f2bf(x0.z) | ((unsigned)f2bf(x0.w) << 16);
        v.z = (unsigned)f2bf(x1.x) | ((unsigned)f2bf(x1.y) << 16);
        v.w = (unsigned)f2bf(x1.z) | ((unsigned)f2bf(x1.w) << 16);
        int slot = (((o >> 4) * 8 + kt) * 64) + quad * 16 + (o & 15);
        ((uint4*)((unsigned short*)(ws + WS_WPB)))[slot] = v;
        // G partials over this thread's 8 c; reduce over the 32 lanes sharing o
        int c0 = idx & 255;
        float xv[8] = {x0.x, x0.y, x0.z, x0.w, x1.x, x1.y, x1.z, x1.w};
        float g0 = 0.f, g1 = 0.f, g2 = 0.f, gb = 0.f;
#pragma unroll
        for (int j = 0; j < 8; ++j) {
            int c = c0 + j;
            g0 = fmaf(xv[j], WvL[c * 3 + 0], g0);
            g1 = fmaf(xv[j], WvL[c * 3 + 1], g1);
            g2 = fmaf(xv[j], WvL[c * 3 + 2], g2);
            gb = fmaf(xv[j], bvL[c], gb);
        }
#pragma unroll
        for (int off = 1; off < 32; off <<= 1) {
            g0 += __shfl_xor(g0, off);
            g1 += __shfl_xor(g1, off);
            g2 += __shfl_xor(g2, off);
            gb += __shfl_xor(gb, off);
        }
        if ((tid & 31) == 0)
            ((float4*)(ws + WS_G4))[o] = make_float4(g0, g1, g2, gb + bp[o]);
    } else {
        // ctx gather: one thread per (b, j)
        int g = (blk - 36) * 256 + tid;             // [0, 32768)
        int b = g >> 10, j = g & 1023;
        int y = j >> 5, x = j & 31;
        const float* src = ctxin + (size_t)b * 150528;
        int p = (7 * y + 3) * 224 + (7 * x + 3);
        ((float4*)(ws + WS_CTX))[g] =
            make_float4(src[p], src[p + 50176], src[p + 100352], 0.f);
    }
}

// ---------- K1: attention path. 1024 blocks = b(32) x i-tile(32 of 32).
// a = M.Q + m0 (shfl+LDS reduce), softmax vs 3-channel LDS ctx, cp -> ws.
// LDS ~14 KB, 2 barriers, no MFMA. ----------
__global__ __launch_bounds__(256, 4) void sca_attn(const float* __restrict__ Q,
                                                   float* __restrict__ ws)
{
    __shared__ float cs0[1024];
    __shared__ float cs1[1024];
    __shared__ float cs2[1024];
    __shared__ float red[4][8][12];       // [wave][iq][t*4+e]
    __shared__ float4 av4[32];

    int tid = threadIdx.x;
    int blk = blockIdx.x;
    int b  = blk >> 5;
    int i0 = (blk & 31) << 5;
    int lane = tid & 63, w = tid >> 6;
    int iq = tid & 7, kg = tid >> 3;      // 4 consecutive i x 32 k-groups (8 k each)

    // ctx -> 3-channel LDS (coalesced float4 from pre-gathered ws)
    {
        const float4* cg4 = ((const float4*)(ws + WS_CTX)) + ((size_t)b << 10);
#pragma unroll
        for (int s4 = 0; s4 < 4; ++s4) {
            int j = s4 * 256 + tid;
            float4 v = cg4[j];
            cs0[j] = v.x; cs1[j] = v.y; cs2[j] = v.z;
        }
    }

    // a-partials over this thread's 8 channels
    const float4* M4 = (const float4*)(ws + WS_M4);
    const float* Qp = Q + ((size_t)b << 18) + ((size_t)(kg * 8) << 10) + i0 + iq * 4;
    float a00=0.f,a01=0.f,a02=0.f,a03=0.f;
    float a10=0.f,a11=0.f,a12=0.f,a13=0.f;
    float a20=0.f,a21=0.f,a22=0.f,a23=0.f;
#pragma unroll
    for (int s = 0; s < 8; ++s) {
        float4 qv = *(const float4*)(Qp + ((size_t)s << 10));
        float4 mv = M4[kg * 8 + s];
        a00 = fmaf(mv.x, qv.x, a00); a01 = fmaf(mv.x, qv.y, a01); a02 = fmaf(mv.x, qv.z, a02); a03 = fmaf(mv.x, qv.w, a03);
        a10 = fmaf(mv.y, qv.x, a10); a11 = fmaf(mv.y, qv.y, a11); a12 = fmaf(mv.y, qv.z, a12); a13 = fmaf(mv.y, qv.w, a13);
        a20 = fmaf(mv.z, qv.x, a20); a21 = fmaf(mv.z, qv.y, a21); a22 = fmaf(mv.z, qv.z, a22); a23 = fmaf(mv.z, qv.w, a23);
    }
    // reduce over kg within wave (lane bits 3,4,5)
    a00 += __shfl_xor(a00,8); a00 += __shfl_xor(a00,16); a00 += __shfl_xor(a00,32);
    a01 += __shfl_xor(a01,8); a01 += __shfl_xor(a01,16); a01 += __shfl_xor(a01,32);
    a02 += __shfl_xor(a02,8); a02 += __shfl_xor(a02,16); a02 += __shfl_xor(a02,32);
    a03 += __shfl_xor(a03,8); a03 += __shfl_xor(a03,16); a03 += __shfl_xor(a03,32);
    a10 += __shfl_xor(a10,8); a10 += __shfl_xor(a10,16); a10 += __shfl_xor(a10,32);
    a11 += __shfl_xor(a11,8); a11 += __shfl_xor(a11,16); a11 += __shfl_xor(a11,32);
    a12 += __shfl_xor(a12,8); a12 += __shfl_xor(a12,16); a12 += __shfl_xor(a12,32);
    a13 += __shfl_xor(a13,8); a13 += __shfl_xor(a13,16); a13 += __shfl_xor(a13,32);
    a20 += __shfl_xor(a20,8); a20 += __shfl_xor(a20,16); a20 += __shfl_xor(a20,32);
    a21 += __shfl_xor(a21,8); a21 += __shfl_xor(a21,16); a21 += __shfl_xor(a21,32);
    a22 += __shfl_xor(a22,8); a22 += __shfl_xor(a22,16); a22 += __shfl_xor(a22,32);
    a23 += __shfl_xor(a23,8); a23 += __shfl_xor(a23,16); a23 += __shfl_xor(a23,32);
    if (lane < 8) {
        red[w][lane][0]=a00; red[w][lane][1]=a01; red[w][lane][2] =a02; red[w][lane][3] =a03;
        red[w][lane][4]=a10; red[w][lane][5]=a11; red[w][lane][6] =a12; red[w][lane][7] =a13;
        red[w][lane][8]=a20; red[w][lane][9]=a21; red[w][lane][10]=a22; red[w][lane][11]=a23;
    }
    __syncthreads();
    if (tid < 32) {
        int iqq = tid >> 2, e = tid & 3;
        float r0 = red[0][iqq][0+e] + red[1][iqq][0+e] + red[2][iqq][0+e] + red[3][iqq][0+e] + ws[WS_M0 + 0];
        float r1 = red[0][iqq][4+e] + red[1][iqq][4+e] + red[2][iqq][4+e] + red[3][iqq][4+e] + ws[WS_M0 + 1];
        float r2 = red[0][iqq][8+e] + red[1][iqq][8+e] + red[2][iqq][8+e] + red[3][iqq][8+e] + ws[WS_M0 + 2];
        av4[tid] = make_float4(r0, r1, r2, 0.f);
    }
    __syncthreads();

    // softmax + cp (8 lanes per query i, single pass, analytic shift)
    {
        int qi = tid >> 3, sl = tid & 7;
        float4 a = av4[qi];
        // |ctx| <= ~5.3 over N(0,1); shift 6*|a|_1 keeps exp args in [-~30, 0].
        float sh = 6.0f * (fabsf(a.x) + fabsf(a.y) + fabsf(a.z));
        float d = 0.f, s0 = 0.f, s1 = 0.f, s2 = 0.f;
#pragma unroll 4
        for (int jj = 0; jj < 128; ++jj) {
            int j = (jj << 3) + sl;
            float c0 = cs0[j], c1 = cs1[j], c2 = cs2[j];
            float sc = fmaf(a.x, c0, fmaf(a.y, c1, a.z * c2));
            float e = __expf(sc - sh);
            d += e;
            s0 = fmaf(e, c0, s0);
            s1 = fmaf(e, c1, s1);
            s2 = fmaf(e, c2, s2);
        }
        d  += __shfl_xor(d, 1);  d  += __shfl_xor(d, 2);  d  += __shfl_xor(d, 4);
        s0 += __shfl_xor(s0, 1); s0 += __shfl_xor(s0, 2); s0 += __shfl_xor(s0, 4);
        s1 += __shfl_xor(s1, 1); s1 += __shfl_xor(s1, 2); s1 += __shfl_xor(s1, 4);
        s2 += __shfl_xor(s2, 1); s2 += __shfl_xor(s2, 2); s2 += __shfl_xor(s2, 4);
        if (sl == 0) {
            float inv = 1.0f / d;
            ((float4*)(ws + WS_CP))[(b << 10) + i0 + qi] =
                make_float4(s0 * inv, s1 * inv, s2 * inv, 0.f);
        }
    }
}

// ---------- K2: GEMM path. 1024 blocks = b(32) x i-tile(32 of 32).
// Q -> bf16 -> 16 KB swizzled QL -> MFMA (wave w: o=w*64..+63) ->
// epilogue + G.cp + stats. ONE barrier. ----------
__global__ __launch_bounds__(256, 4) void sca_gemm(const float* __restrict__ Q,
                                                   float* __restrict__ ws,
                                                   float* __restrict__ out)
{
    __shared__ uint4 QL[1024];            // 32 rows x 32 16B-groups, XOR-swizzled

    int tid = threadIdx.x;
    int blk = blockIdx.x;
    int b  = blk >> 5;
    int i0 = (blk & 31) << 5;
    int lane = tid & 63, w = tid >> 6;
    int iq = tid & 7, kg = tid >> 3;      // 4 consecutive i x 32 k-groups (8 k each)

    // Q load + bf16 pack
    const float* Qp = Q + ((size_t)b << 18) + ((size_t)(kg * 8) << 10) + i0 + iq * 4;
    unsigned pk[4][4];                    // [e][pair]
#pragma unroll
    for (int s = 0; s < 8; ++s) {
        float4 qv = *(const float4*)(Qp + ((size_t)s << 10));
        unsigned h0 = f2bf(qv.x), h1 = f2bf(qv.y), h2 = f2bf(qv.z), h3 = f2bf(qv.w);
        int j = s >> 1;
        if (s & 1) {
            pk[0][j] |= h0 << 16; pk[1][j] |= h1 << 16;
            pk[2][j] |= h2 << 16; pk[3][j] |= h3 << 16;
        } else {
            pk[0][j] = h0; pk[1][j] = h1; pk[2][j] = h2; pk[3][j] = h3;
        }
    }
    // swizzled QL write: row = local i, group g = kg (8 k = 16 B)
#pragma unroll
    for (int e = 0; e < 4; ++e) {
        int row = iq * 4 + e;
        int sw = (row ^ (row >> 3)) & 7;
        int gs = (kg & 24) | ((kg ^ sw) & 7);
        QL[row * 32 + gs] = make_uint4(pk[e][0], pk[e][1], pk[e][2], pk[e][3]);
    }
    __syncthreads();

    // MFMA K-loop: wave w covers o = w*64..w*64+63, all 32 i of this block
    int m = lane & 15, quad = lane >> 4;
    const short8* Apack = (const short8*)((const unsigned short*)(ws + WS_WPB));
    const short8* QLs = (const short8*)QL;
    floatx4 acc[4][2] = {};
#pragma unroll
    for (int kt = 0; kt < 8; ++kt) {
        short8 af[4], bf[2];
#pragma unroll
        for (int t = 0; t < 4; ++t)
            af[t] = Apack[((w * 4 + t) * 8 + kt) * 64 + lane];
#pragma unroll
        for (int t = 0; t < 2; ++t) {
            int row = t * 16 + m;
            int sw = (row ^ (row >> 3)) & 7;
            int g = kt * 4 + quad;
            int gs = (g & 24) | ((g ^ sw) & 7);
            bf[t] = QLs[row * 32 + gs];
        }
#pragma unroll
        for (int to = 0; to < 4; ++to)
#pragma unroll
            for (int ti = 0; ti < 2; ++ti)
                acc[to][ti] = __builtin_amdgcn_mfma_f32_16x16x32_bf16(
                    af[to], bf[ti], acc[to][ti], 0, 0, 0);
    }

    // epilogue: rank-3 + bias, store, GroupNorm partial stats
    const floatx4* G4 = (const floatx4*)(ws + WS_G4);
    const float4* CP4 = ((const float4*)(ws + WS_CP)) + ((size_t)b << 10) + i0;
    float4 cpv[2];
#pragma unroll
    for (int ti = 0; ti < 2; ++ti) cpv[ti] = CP4[ti * 16 + m];
    float lsum = 0.f, lssq = 0.f;
#pragma unroll
    for (int to = 0; to < 4; ++to)
#pragma unroll
        for (int r = 0; r < 4; ++r) {
            int o = w * 64 + to * 16 + quad * 4 + r;
            floatx4 g = G4[o];
            float* orow = out + (((size_t)(b * 256 + o)) << 10) + i0 + m;
#pragma unroll
            for (int ti = 0; ti < 2; ++ti) {
                float v = acc[to][ti][r]
                        + g[0] * cpv[ti].x + g[1] * cpv[ti].y + g[2] * cpv[ti].z + g[3];
                orow[ti * 16] = v;
                lsum += v; lssq = fmaf(v, v, lssq);
            }
        }
#pragma unroll
    for (int off = 32; off > 0; off >>= 1) {
        lsum += __shfl_down(lsum, off);
        lssq += __shfl_down(lssq, off);
    }
    if (lane == 0) {
        atomicAdd(ws + WS_BSUM + b, lsum);
        atomicAdd(ws + WS_BSSQ + b, lssq);
    }
}

// ---------- K3: GroupNorm(1 group) normalize in place (grid-stride x4) ----------
__global__ __launch_bounds__(256) void sca_norm(float* __restrict__ out,
                                                const float* __restrict__ ws,
                                                const float* __restrict__ gamma,
                                                const float* __restrict__ beta)
{
    const float inv_n = 1.0f / 262144.0f;
#pragma unroll
    for (int r = 0; r < 4; ++r) {
        size_t idx = (size_t)r * 524288 + (size_t)blockIdx.x * 256 + threadIdx.x;
        float4 v = ((const float4*)out)[idx];
        size_t base = idx << 2;
        int b = (int)(base >> 18);
        int o = (int)((base >> 10) & 255);
        float mean = ws[WS_BSUM + b] * inv_n;
        float var  = fmaf(ws[WS_BSSQ + b], inv_n, -mean * mean);
        float rs = rsqrtf(var + 1e-5f);
        float ga = gamma[o] * rs;
        float be = fmaf(-mean, ga, beta[o]);
        v.x = fmaf(v.x, ga, be);
        v.y = fmaf(v.y, ga, be);
        v.z = fmaf(v.z, ga, be);
        v.w = fmaf(v.w, ga, be);
        ((float4*)out)[idx] = v;
    }
}

extern "C" void kernel_launch(void* const* d_in, const int* in_sizes, int n_in,
                              void* d_out, int out_size, void* d_ws, size_t ws_size,
                              hipStream_t stream)
{
    const float* Q     = (const float*)d_in[0];
    const float* ctxf  = (const float*)d_in[1];
    const float* Wq    = (const float*)d_in[2];
    const float* bq    = (const float*)d_in[3];
    const float* Wk    = (const float*)d_in[4];
    const float* bk    = (const float*)d_in[5];
    const float* Wv    = (const float*)d_in[6];
    const float* bv    = (const float*)d_in[7];
    const float* Wp    = (const float*)d_in[8];
    const float* bp    = (const float*)d_in[9];
    const float* gamma = (const float*)d_in[10];
    const float* beta  = (const float*)d_in[11];
    float* ws  = (float*)d_ws;
    float* out = (float*)d_out;

    sca_pre <<<164,  256, 0, stream>>>(Wq, bq, Wk, bk, Wv, bv, Wp, bp, ctxf, ws);
    sca_attn<<<1024, 256, 0, stream>>>(Q, ws);
    sca_gemm<<<1024, 256, 0, stream>>>(Q, ws, out);
    sca_norm<<<2048, 256, 0, stream>>>(out, ws, gamma, beta);
}

// Round 6
// 160.487 us; speedup vs baseline: 1.1610x; 1.1610x over previous
//
#include <hip/hip_runtime.h>
#include <hip/hip_bf16.h>

// B=32, CQ=256, CC=3, COUT=256, H=W=32, HW=1024, INTER=128
//
// Math (verified rounds 0-5, absmax 0.031):
//   scores[i,j] = a[:,i]·ctx[:,j] + c_i (softmax-invariant const dropped)
//     a = M·Q + m0, M = Wk^T Wq (3x256)
//   fused = Wp·Q + G·cp + g0;  G = Wp·Wv (256x3), cp[t,i] = sum_j ctx[t,j]P[i,j]
//   resize 224->32 half-pixel = exact gather at (7y+3, 7x+3).
//
// R11: R10 post-mortem -- three different structures all plateau at ~1 TB/s
// effective HBM (R6 62MB/61us, R9 53/58, R10-gemm 51/55) while norm
// (float4-linear) streams fast. Diagnosis: 128B-per-4KB access granularity
// (i-tile<=64) caps DRAM efficiency. Fix: panel GEMM. Block = (b, o-half 128,
// i-quarter 256), 512 thr. Q staged per 64-k chunk: ONE 1KB row per
// wave-instr (fully contiguous), bf16 QL [i256][oct8] with XOR swizzle
// gs = g ^ (i&7) ^ ((i>>2)&7) (write: 8 distinct banks/instr; read: canonical).
// Stores: 1 KB per o-row per block. Same MFMA frag math as R6 (Apack
// unchanged). Atomics: one pair per block (was per wave).
//
// Workspace (float offsets):
#define WS_M4    0        // M4[c] = {m0,m1,m2,0}  c<256  (float4)
#define WS_M0    1024     // m0[3]
#define WS_G4    1056     // G4[o] = {G0,G1,G2,g0} (float4)
#define WS_BSUM  2080     // [32]
#define WS_BSSQ  2112     // [32]
#define WS_WPB   2144     // Wp bf16 fragment-packed [o_tile16][kt8][lane64][8]
#define WS_CP    34912    // cp float4 {p0,p1,p2,0} [b32][i1024]  (512 KB)
#define WS_CTX   165984   // ctx float4 {c0,c1,c2,0} [b32][j1024] (512 KB)

typedef __attribute__((ext_vector_type(8))) short short8;
typedef __attribute__((ext_vector_type(4))) float floatx4;

__device__ inline unsigned short f2bf(float x) {
    unsigned u = __float_as_uint(x);
    return (unsigned short)((u + 0x7FFFu + ((u >> 16) & 1u)) >> 16);
}

// ---------- K0: weight precompute + Wp fragment-pack + ctx pre-gather ----------
// blocks 0..3: M quarters (float4 layout); block 0 also m0 + stats zero
// blocks 4..35: Wp bf16 pack + G = Wp*Wv via lane reduction
// blocks 36..163: ctx bilinear-gather -> ws
__global__ __launch_bounds__(256) void sca_pre(
    const float* __restrict__ Wq, const float* __restrict__ bq,
    const float* __restrict__ Wk, const float* __restrict__ bk,
    const float* __restrict__ Wv, const float* __restrict__ bv,
    const float* __restrict__ Wp, const float* __restrict__ bp,
    const float* __restrict__ ctxin, float* __restrict__ ws)
{
    int tid = threadIdx.x;
    int blk = blockIdx.x;
    if (blk < 4) {
        __shared__ float WkL[384];
        __shared__ float bqL[128];
        __shared__ float redM[4][64][3];
        int o0 = blk << 6;
        if (tid < 128) bqL[tid] = bq[tid];
        for (int idx = tid; idx < 384; idx += 256) WkL[idx] = Wk[idx];
        __syncthreads();
        int o64 = tid & 63, cg = tid >> 6;
        float m0v = 0.f, m1v = 0.f, m2v = 0.f;
        for (int c0 = cg * 32; c0 < cg * 32 + 32; c0 += 16) {
            float q[16];
#pragma unroll
            for (int j = 0; j < 16; ++j) q[j] = Wq[(c0 + j) * 256 + o0 + o64];
#pragma unroll
            for (int j = 0; j < 16; ++j) {
                int c = c0 + j;
                m0v = fmaf(WkL[c * 3 + 0], q[j], m0v);
                m1v = fmaf(WkL[c * 3 + 1], q[j], m1v);
                m2v = fmaf(WkL[c * 3 + 2], q[j], m2v);
            }
        }
        redM[cg][o64][0] = m0v; redM[cg][o64][1] = m1v; redM[cg][o64][2] = m2v;
        __syncthreads();
        if (tid < 64) {
            float r0 = redM[0][tid][0] + redM[1][tid][0] + redM[2][tid][0] + redM[3][tid][0];
            float r1 = redM[0][tid][1] + redM[1][tid][1] + redM[2][tid][1] + redM[3][tid][1];
            float r2 = redM[0][tid][2] + redM[1][tid][2] + redM[2][tid][2] + redM[3][tid][2];
            ((float4*)(ws + WS_M4))[o0 + tid] = make_float4(r0, r1, r2, 0.f);
        }
        if (blk == 0) {
            if (tid < 3) {
                float s = 0.f;
                for (int c = 0; c < 128; ++c) s = fmaf(WkL[c * 3 + tid], bqL[c], s);
                ws[WS_M0 + tid] = s;
            }
            if (tid < 64) ws[WS_BSUM + tid] = 0.f;   // bsum[32]+bssq[32]
        }
    } else if (blk < 36) {
        __shared__ float WvL[768];
        __shared__ float bvL[256];
        for (int idx = tid; idx < 768; idx += 256) WvL[idx] = Wv[idx];
        bvL[tid] = bv[tid];
        __syncthreads();
        int idx = (blk - 4) * 2048 + tid * 8;       // flat [o][k] element index
        int o = idx >> 8;
        int kt = (tid & 31) >> 2, quad = tid & 3;
        const float4* s = (const float4*)(Wp + idx);
        float4 x0 = s[0], x1 = s[1];
        uint4 v;
        v.x = (unsigned)f2bf(x0.x) | ((unsigned)f2bf(x0.y) << 16);
        v.y = (unsigned)f2bf(x0.z) | ((unsigned)f2bf(x0.w) << 16);
        v.z = (unsigned)f2bf(x1.x) | ((unsigned)f2bf(x1.y) << 16);
        v.w = (unsigned)f2bf(x1.z) | ((unsigned)f2bf(x1.w) << 16);
        int slot = (((o >> 4) * 8 + kt) * 64) + quad * 16 + (o & 15);
        ((uint4*)((unsigned short*)(ws + WS_WPB)))[slot] = v;
        // G partials over this thread's 8 c; reduce over the 32 lanes sharing o
        int c0 = idx & 255;
        float xv[8] = {x0.x, x0.y, x0.z, x0.w, x1.x, x1.y, x1.z, x1.w};
        float g0 = 0.f, g1 = 0.f, g2 = 0.f, gb = 0.f;
#pragma unroll
        for (int j = 0; j < 8; ++j) {
            int c = c0 + j;
            g0 = fmaf(xv[j], WvL[c * 3 + 0], g0);
            g1 = fmaf(xv[j], WvL[c * 3 + 1], g1);
            g2 = fmaf(xv[j], WvL[c * 3 + 2], g2);
            gb = fmaf(xv[j], bvL[c], gb);
        }
#pragma unroll
        for (int off = 1; off < 32; off <<= 1) {
            g0 += __shfl_xor(g0, off);
            g1 += __shfl_xor(g1, off);
            g2 += __shfl_xor(g2, off);
            gb += __shfl_xor(gb, off);
        }
        if ((tid & 31) == 0)
            ((float4*)(ws + WS_G4))[o] = make_float4(g0, g1, g2, gb + bp[o]);
    } else {
        // ctx gather: one thread per (b, j)
        int g = (blk - 36) * 256 + tid;             // [0, 32768)
        int b = g >> 10, j = g & 1023;
        int y = j >> 5, x = j & 31;
        const float* src = ctxin + (size_t)b * 150528;
        int p = (7 * y + 3) * 224 + (7 * x + 3);
        ((float4*)(ws + WS_CTX))[g] =
            make_float4(src[p], src[p + 50176], src[p + 100352], 0.f);
    }
}

// ---------- K1: attention path. 1024 blocks = b(32) x i-tile(32 of 32).
// a = M.Q + m0 (shfl+LDS reduce), softmax vs 3-channel LDS ctx, cp -> ws.
// (unchanged from R10; gets the streaming treatment next round if R11's
// granularity theory confirms on the gemm.) ----------
__global__ __launch_bounds__(256, 4) void sca_attn(const float* __restrict__ Q,
                                                   float* __restrict__ ws)
{
    __shared__ float cs0[1024];
    __shared__ float cs1[1024];
    __shared__ float cs2[1024];
    __shared__ float red[4][8][12];       // [wave][iq][t*4+e]
    __shared__ float4 av4[32];

    int tid = threadIdx.x;
    int blk = blockIdx.x;
    int b  = blk >> 5;
    int i0 = (blk & 31) << 5;
    int lane = tid & 63, w = tid >> 6;
    int iq = tid & 7, kg = tid >> 3;      // 4 consecutive i x 32 k-groups (8 k each)

    // ctx -> 3-channel LDS (coalesced float4 from pre-gathered ws)
    {
        const float4* cg4 = ((const float4*)(ws + WS_CTX)) + ((size_t)b << 10);
#pragma unroll
        for (int s4 = 0; s4 < 4; ++s4) {
            int j = s4 * 256 + tid;
            float4 v = cg4[j];
            cs0[j] = v.x; cs1[j] = v.y; cs2[j] = v.z;
        }
    }

    // a-partials over this thread's 8 channels
    const float4* M4 = (const float4*)(ws + WS_M4);
    const float* Qp = Q + ((size_t)b << 18) + ((size_t)(kg * 8) << 10) + i0 + iq * 4;
    float a00=0.f,a01=0.f,a02=0.f,a03=0.f;
    float a10=0.f,a11=0.f,a12=0.f,a13=0.f;
    float a20=0.f,a21=0.f,a22=0.f,a23=0.f;
#pragma unroll
    for (int s = 0; s < 8; ++s) {
        float4 qv = *(const float4*)(Qp + ((size_t)s << 10));
        float4 mv = M4[kg * 8 + s];
        a00 = fmaf(mv.x, qv.x, a00); a01 = fmaf(mv.x, qv.y, a01); a02 = fmaf(mv.x, qv.z, a02); a03 = fmaf(mv.x, qv.w, a03);
        a10 = fmaf(mv.y, qv.x, a10); a11 = fmaf(mv.y, qv.y, a11); a12 = fmaf(mv.y, qv.z, a12); a13 = fmaf(mv.y, qv.w, a13);
        a20 = fmaf(mv.z, qv.x, a20); a21 = fmaf(mv.z, qv.y, a21); a22 = fmaf(mv.z, qv.z, a22); a23 = fmaf(mv.z, qv.w, a23);
    }
    // reduce over kg within wave (lane bits 3,4,5)
    a00 += __shfl_xor(a00,8); a00 += __shfl_xor(a00,16); a00 += __shfl_xor(a00,32);
    a01 += __shfl_xor(a01,8); a01 += __shfl_xor(a01,16); a01 += __shfl_xor(a01,32);
    a02 += __shfl_xor(a02,8); a02 += __shfl_xor(a02,16); a02 += __shfl_xor(a02,32);
    a03 += __shfl_xor(a03,8); a03 += __shfl_xor(a03,16); a03 += __shfl_xor(a03,32);
    a10 += __shfl_xor(a10,8); a10 += __shfl_xor(a10,16); a10 += __shfl_xor(a10,32);
    a11 += __shfl_xor(a11,8); a11 += __shfl_xor(a11,16); a11 += __shfl_xor(a11,32);
    a12 += __shfl_xor(a12,8); a12 += __shfl_xor(a12,16); a12 += __shfl_xor(a12,32);
    a13 += __shfl_xor(a13,8); a13 += __shfl_xor(a13,16); a13 += __shfl_xor(a13,32);
    a20 += __shfl_xor(a20,8); a20 += __shfl_xor(a20,16); a20 += __shfl_xor(a20,32);
    a21 += __shfl_xor(a21,8); a21 += __shfl_xor(a21,16); a21 += __shfl_xor(a21,32);
    a22 += __shfl_xor(a22,8); a22 += __shfl_xor(a22,16); a22 += __shfl_xor(a22,32);
    a23 += __shfl_xor(a23,8); a23 += __shfl_xor(a23,16); a23 += __shfl_xor(a23,32);
    if (lane < 8) {
        red[w][lane][0]=a00; red[w][lane][1]=a01; red[w][lane][2] =a02; red[w][lane][3] =a03;
        red[w][lane][4]=a10; red[w][lane][5]=a11; red[w][lane][6] =a12; red[w][lane][7] =a13;
        red[w][lane][8]=a20; red[w][lane][9]=a21; red[w][lane][10]=a22; red[w][lane][11]=a23;
    }
    __syncthreads();
    if (tid < 32) {
        int iqq = tid >> 2, e = tid & 3;
        float r0 = red[0][iqq][0+e] + red[1][iqq][0+e] + red[2][iqq][0+e] + red[3][iqq][0+e] + ws[WS_M0 + 0];
        float r1 = red[0][iqq][4+e] + red[1][iqq][4+e] + red[2][iqq][4+e] + red[3][iqq][4+e] + ws[WS_M0 + 1];
        float r2 = red[0][iqq][8+e] + red[1][iqq][8+e] + red[2][iqq][8+e] + red[3][iqq][8+e] + ws[WS_M0 + 2];
        av4[tid] = make_float4(r0, r1, r2, 0.f);
    }
    __syncthreads();

    // softmax + cp (8 lanes per query i, single pass, analytic shift)
    {
        int qi = tid >> 3, sl = tid & 7;
        float4 a = av4[qi];
        // |ctx| <= ~5.3 over N(0,1); shift 6*|a|_1 keeps exp args in [-~30, 0].
        float sh = 6.0f * (fabsf(a.x) + fabsf(a.y) + fabsf(a.z));
        float d = 0.f, s0 = 0.f, s1 = 0.f, s2 = 0.f;
#pragma unroll 4
        for (int jj = 0; jj < 128; ++jj) {
            int j = (jj << 3) + sl;
            float c0 = cs0[j], c1 = cs1[j], c2 = cs2[j];
            float sc = fmaf(a.x, c0, fmaf(a.y, c1, a.z * c2));
            float e = __expf(sc - sh);
            d += e;
            s0 = fmaf(e, c0, s0);
            s1 = fmaf(e, c1, s1);
            s2 = fmaf(e, c2, s2);
        }
        d  += __shfl_xor(d, 1);  d  += __shfl_xor(d, 2);  d  += __shfl_xor(d, 4);
        s0 += __shfl_xor(s0, 1); s0 += __shfl_xor(s0, 2); s0 += __shfl_xor(s0, 4);
        s1 += __shfl_xor(s1, 1); s1 += __shfl_xor(s1, 2); s1 += __shfl_xor(s1, 4);
        s2 += __shfl_xor(s2, 1); s2 += __shfl_xor(s2, 2); s2 += __shfl_xor(s2, 4);
        if (sl == 0) {
            float inv = 1.0f / d;
            ((float4*)(ws + WS_CP))[(b << 10) + i0 + qi] =
                make_float4(s0 * inv, s1 * inv, s2 * inv, 0.f);
        }
    }
}

// ---------- K2: panel GEMM. 256 blocks = b(32) x o-half(2) x i-quarter(4).
// 512 thr (8 waves). Per 64-k chunk: wave w streams 8 full 1KB k-rows
// (k = c*64 + w*8 + s, lane covers i = 4*lane..+3) -> bf16 QL [i256][oct8]
// swizzled gs = g ^ (i&7) ^ ((i>>2)&7) -> 32 MFMAs. Wave w owns o-tile 16.
// Stores: 1 KB per o-row per block. One atomic pair per block. ----------
__global__ __launch_bounds__(512, 2) void sca_gemm(const float* __restrict__ Q,
                                                   float* __restrict__ ws,
                                                   float* __restrict__ out)
{
    __shared__ uint4 QL[2048];            // [i 256][g 8] 16B groups, 32 KB
    __shared__ float sred[16];

    int tid = threadIdx.x;
    int blk = blockIdx.x;                  // 256 = b(32) x oh(2) x iq(4)
    int b  = blk >> 3;
    int oh = (blk >> 2) & 1;
    int i0 = (blk & 3) << 8;
    int lane = tid & 63, w = tid >> 6;     // 8 waves
    int m = lane & 15, quad = lane >> 4;

    const short8* Apack = (const short8*)((const unsigned short*)(ws + WS_WPB));
    int otile = oh * 8 + w;                // global o-tile16 of this wave

    floatx4 acc[16] = {};
    const float* Qbase = Q + ((size_t)b << 18) + i0 + (lane << 2);

    for (int c = 0; c < 4; ++c) {
        // stream 8 full k-rows: one 1 KB contiguous row per wave-instruction
        float4 qv[8];
#pragma unroll
        for (int s = 0; s < 8; ++s)
            qv[s] = *(const float4*)(Qbase + ((size_t)(c * 64 + w * 8 + s) << 10));
        __syncthreads();                   // prev chunk's QL reads complete
        // pack: thread holds (8 consecutive k = c*64+w*8.., 4 i = 4*lane..+3)
#pragma unroll
        for (int e = 0; e < 4; ++e) {
            const float* q0 = (const float*)&qv[0];
            uint4 v;
            v.x = (unsigned)f2bf(((const float*)&qv[0])[e]) | ((unsigned)f2bf(((const float*)&qv[1])[e]) << 16);
            v.y = (unsigned)f2bf(((const float*)&qv[2])[e]) | ((unsigned)f2bf(((const float*)&qv[3])[e]) << 16);
            v.z = (unsigned)f2bf(((const float*)&qv[4])[e]) | ((unsigned)f2bf(((const float*)&qv[5])[e]) << 16);
            v.w = (unsigned)f2bf(((const float*)&qv[6])[e]) | ((unsigned)f2bf(((const float*)&qv[7])[e]) << 16);
            int i = (lane << 2) + e;
            int gs = w ^ (i & 7) ^ ((i >> 2) & 7);
            QL[i * 8 + gs] = v;
            (void)q0;
        }
        __syncthreads();                   // QL visible
        // MFMA: two K=32 slices of this chunk
#pragma unroll
        for (int kk = 0; kk < 2; ++kk) {
            short8 af = Apack[((otile * 8) + (c * 2 + kk)) * 64 + lane];
#pragma unroll
            for (int it = 0; it < 16; ++it) {
                int i = it * 16 + m;
                int g = kk * 4 + quad;
                int gs = g ^ (i & 7) ^ ((i >> 2) & 7);
                short8 bf = ((const short8*)QL)[i * 8 + gs];
                acc[it] = __builtin_amdgcn_mfma_f32_16x16x32_bf16(
                    af, bf, acc[it], 0, 0, 0);
            }
        }
    }

    // ---- epilogue: rank-3 + bias, store (1 KB/row), block stats ----
    const floatx4* G4 = (const floatx4*)(ws + WS_G4);
    const float4* CP4 = ((const float4*)(ws + WS_CP)) + ((size_t)b << 10) + i0;
    floatx4 gv[4];
#pragma unroll
    for (int r = 0; r < 4; ++r) gv[r] = G4[oh * 128 + w * 16 + quad * 4 + r];
    float lsum = 0.f, lssq = 0.f;
#pragma unroll
    for (int it = 0; it < 16; ++it) {
        float4 cp = CP4[it * 16 + m];
#pragma unroll
        for (int r = 0; r < 4; ++r) {
            int o = oh * 128 + w * 16 + quad * 4 + r;
            float v = acc[it][r]
                    + gv[r][0] * cp.x + gv[r][1] * cp.y + gv[r][2] * cp.z + gv[r][3];
            out[(((size_t)(b * 256 + o)) << 10) + i0 + it * 16 + m] = v;
            lsum += v; lssq = fmaf(v, v, lssq);
        }
    }
#pragma unroll
    for (int off = 32; off > 0; off >>= 1) {
        lsum += __shfl_down(lsum, off);
        lssq += __shfl_down(lssq, off);
    }
    if (lane == 0) { sred[w] = lsum; sred[8 + w] = lssq; }
    __syncthreads();
    if (tid == 0) {
        float s = 0.f, q2 = 0.f;
#pragma unroll
        for (int j = 0; j < 8; ++j) { s += sred[j]; q2 += sred[8 + j]; }
        atomicAdd(ws + WS_BSUM + b, s);
        atomicAdd(ws + WS_BSSQ + b, q2);
    }
}

// ---------- K3: GroupNorm(1 group) normalize in place (grid-stride x4) ----------
__global__ __launch_bounds__(256) void sca_norm(float* __restrict__ out,
                                                const float* __restrict__ ws,
                                                const float* __restrict__ gamma,
                                                const float* __restrict__ beta)
{
    const float inv_n = 1.0f / 262144.0f;
#pragma unroll
    for (int r = 0; r < 4; ++r) {
        size_t idx = (size_t)r * 524288 + (size_t)blockIdx.x * 256 + threadIdx.x;
        float4 v = ((const float4*)out)[idx];
        size_t base = idx << 2;
        int b = (int)(base >> 18);
        int o = (int)((base >> 10) & 255);
        float mean = ws[WS_BSUM + b] * inv_n;
        float var  = fmaf(ws[WS_BSSQ + b], inv_n, -mean * mean);
        float rs = rsqrtf(var + 1e-5f);
        float ga = gamma[o] * rs;
        float be = fmaf(-mean, ga, beta[o]);
        v.x = fmaf(v.x, ga, be);
        v.y = fmaf(v.y, ga, be);
        v.z = fmaf(v.z, ga, be);
        v.w = fmaf(v.w, ga, be);
        ((float4*)out)[idx] = v;
    }
}

extern "C" void kernel_launch(void* const* d_in, const int* in_sizes, int n_in,
                              void* d_out, int out_size, void* d_ws, size_t ws_size,
                              hipStream_t stream)
{
    const float* Q     = (const float*)d_in[0];
    const float* ctxf  = (const float*)d_in[1];
    const float* Wq    = (const float*)d_in[2];
    const float* bq    = (const float*)d_in[3];
    const float* Wk    = (const float*)d_in[4];
    const float* bk    = (const float*)d_in[5];
    const float* Wv    = (const float*)d_in[6];
    const float* bv    = (const float*)d_in[7];
    const float* Wp    = (const float*)d_in[8];
    const float* bp    = (const float*)d_in[9];
    const float* gamma = (const float*)d_in[10];
    const float* beta  = (const float*)d_in[11];
    float* ws  = (float*)d_ws;
    float* out = (float*)d_out;

    sca_pre <<<164,  256, 0, stream>>>(Wq, bq, Wk, bk, Wv, bv, Wp, bp, ctxf, ws);
    sca_attn<<<1024, 256, 0, stream>>>(Q, ws);
    sca_gemm<<<256,  512, 0, stream>>>(Q, ws, out);
    sca_norm<<<2048, 256, 0, stream>>>(out, ws, gamma, beta);
}